// Round 4
// baseline (346.660 us; speedup 1.0000x reference)
//
#include <hip/hip_runtime.h>
#include <hip/hip_bf16.h>

#define NB 8
#define N1 2048
#define N2 1152
#define KD 1024
#define BM 256
#define BN 144
#define BNP 145  // padded epilogue stride

typedef __attribute__((ext_vector_type(4))) float f32x4;
typedef __attribute__((ext_vector_type(2))) long i64x2;

__device__ __forceinline__ unsigned pack4_fp8(float4 v) {
  int t = __builtin_amdgcn_cvt_pk_fp8_f32(v.x, v.y, 0, false);
  t = __builtin_amdgcn_cvt_pk_fp8_f32(v.z, v.w, t, true);
  return (unsigned)t;
}

// One WAVE per row. CONTIGUOUS float4 reads (k = 4*lane + 256*i); the k-block
// permutation is applied on the 4-byte fp8 write instead (writes fully tile a
// contiguous 256 B region per wave-instruction -> coalesced).
// Permuted layout per 64-value k-block: 16B group q holds k=[q*8..q*8+7] ++
// [32+q*8..32+q*8+7], so one b128 LDS read = both k-half MFMA fragments.
__global__ __launch_bounds__(256) void convert_kernel(
    const float* __restrict__ x1, const float* __restrict__ x2,
    unsigned char* __restrict__ x1q, unsigned char* __restrict__ x2q,
    float* __restrict__ sq1, float* __restrict__ sq2) {
  int wave = threadIdx.x >> 6, lane = threadIdx.x & 63;
  int row = blockIdx.x * 4 + wave;
  const float* src;
  unsigned char* dst;
  float* sqp;
  if (row < NB * N1) {
    src = x1 + (size_t)row * KD;
    dst = x1q + (size_t)row * KD;
    sqp = sq1 + row;
  } else {
    int r = row - NB * N1;
    src = x2 + (size_t)r * KD;
    dst = x2q + (size_t)r * KD;
    sqp = sq2 + r;
  }
  const float4* s4 = (const float4*)src;
  // lane covers k = i*256 + 4*lane .. +3  ->  k-block kb = i*4 + (lane>>4),
  // within-block byte r = 4*(lane&15); permuted pos = q*16 + h*8 + (r&7).
  int r = 4 * (lane & 15);
  int q = (r & 31) >> 3;
  int h = r >> 5;
  int pos = (lane >> 4) * 64 + q * 16 + h * 8 + (r & 7);
  float s = 0.f;
#pragma unroll
  for (int i = 0; i < 4; ++i) {
    float4 v = s4[i * 64 + lane];
    *(unsigned*)(dst + i * 256 + pos) = pack4_fp8(v);
    s += v.x * v.x + v.y * v.y + v.z * v.z + v.w * v.w;
  }
#pragma unroll
  for (int off = 32; off > 0; off >>= 1) s += __shfl_down(s, off);
  if (lane == 0) *sqp = s;
}

__device__ __forceinline__ void async_copy16(const void* g, void* l) {
  __builtin_amdgcn_global_load_lds(
      (const __attribute__((address_space(1))) unsigned int*)g,
      (__attribute__((address_space(3))) unsigned int*)l, 16, 0, 0);
}

// Fused fp8 distance + group-min(9) + mean.
// Block tile 256(M) x 144(N), 4 waves; wave owns 64 M-rows = 4x9 acc tiles.
// __launch_bounds__(256,2): min 2 waves/EU -> 256-VGPR budget, NO acc spill
// (R2/R3 regression: default heuristic capped VGPRs at 120/84 and spilled
// the accumulators to scratch every K-iter -> GBs of WRITE_SIZE).
// K-step 64 (fp8, 16 iters). LDS chunks 1 KB = 16 rows x 64 fp8, XOR swizzle
// (slot ^ (row>>1)&3) -> conflict-free b128 fragment reads (verified R2/R3).
__global__ __launch_bounds__(256, 2) void dist_kernel(
    const unsigned char* __restrict__ x1q, const unsigned char* __restrict__ x2q,
    const float* __restrict__ sq1, const float* __restrict__ sq2,
    float* __restrict__ out) {
  __shared__ __align__(16) char smem[64 * BNP * 4];  // 37120 B; staging uses 25600 B

  const int tid = threadIdx.x;
  const int wave = tid >> 6, lane = tid & 63;
  const int bm = blockIdx.x, bn = blockIdx.y, b = blockIdx.z;

  const unsigned char* Ag = x1q + ((size_t)b * N1 + bm * BM) * KD;
  const unsigned char* Bg = x2q + ((size_t)b * N2 + bn * BN) * KD;

  // staging: lane -> (row lr, 16B slot sl), fetch the swizzled global group
  const int lr = lane >> 2, sl = lane & 3;
  const int goff = (sl ^ ((lr >> 1) & 3)) * 16;

  // fragments: lane (fr, quad) reads swizzled slot -> global 16B group `quad`
  const int quad = lane >> 4, fr = lane & 15;
  const int fslot = (fr * 4 + (quad ^ ((fr >> 1) & 3))) * 16;

  f32x4 acc[4][9];
#pragma unroll
  for (int i = 0; i < 4; ++i)
#pragma unroll
    for (int j = 0; j < 9; ++j) {
      f32x4 z = {0.f, 0.f, 0.f, 0.f};
      acc[i][j] = z;
    }

  for (int k0 = 0; k0 < KD; k0 += 64) {
    // 25 chunks: 0..15 = A (256 rows), 16..24 = B (144 rows)
#pragma unroll 1
    for (int j = wave; j < 25; j += 4) {
      const unsigned char* g;
      if (j < 16)
        g = Ag + (size_t)(j * 16 + lr) * KD + k0 + goff;
      else
        g = Bg + (size_t)((j - 16) * 16 + lr) * KD + k0 + goff;
      async_copy16(g, smem + j * 1024 + lane * 16);
    }
    __syncthreads();

    i64x2 a[4];
#pragma unroll
    for (int tm = 0; tm < 4; ++tm)
      a[tm] = *(const i64x2*)(smem + (wave * 4 + tm) * 1024 + fslot);
#pragma unroll
    for (int tn = 0; tn < 9; ++tn) {
      i64x2 bf = *(const i64x2*)(smem + 16384 + tn * 1024 + fslot);
#pragma unroll
      for (int tm = 0; tm < 4; ++tm) {
        acc[tm][tn] = __builtin_amdgcn_mfma_f32_16x16x32_fp8_fp8(a[tm].x, bf.x, acc[tm][tn], 0, 0, 0);
        acc[tm][tn] = __builtin_amdgcn_mfma_f32_16x16x32_fp8_fp8(a[tm].y, bf.y, acc[tm][tn], 0, 0, 0);
      }
    }
    __syncthreads();
  }

  // ---- epilogue: d = sq1 + sq2 - 2*cross, min over 9-col groups, sum ----
  float s2[9];
#pragma unroll
  for (int tn = 0; tn < 9; ++tn)
    s2[tn] = sq2[(size_t)b * N2 + bn * BN + tn * 16 + fr];

  float s1v[4][4];
#pragma unroll
  for (int tm = 0; tm < 4; ++tm)
#pragma unroll
    for (int r = 0; r < 4; ++r)
      s1v[tm][r] = sq1[(size_t)b * N1 + bm * BM + wave * 64 + tm * 16 + quad * 4 + r];

  float* eps = (float*)smem;
  float local = 0.f;
#pragma unroll 1
  for (int tm = 0; tm < 4; ++tm) {
    __syncthreads();  // previous chunk / K-loop LDS fully consumed
    // D layout (16x16x32, dtype-independent): col = lane&15 (x2 row),
    // row = quad*4 + reg (x1 row). Chunk row = wave*16 + quad*4 + r.
#pragma unroll
    for (int tn = 0; tn < 9; ++tn)
#pragma unroll
      for (int r = 0; r < 4; ++r)
        eps[(wave * 16 + quad * 4 + r) * BNP + tn * 16 + fr] =
            s1v[tm][r] + s2[tn] - 2.0f * acc[tm][tn][r];
    __syncthreads();
    // 64 rows x 16 groups = 1024 groups, 4 per thread
#pragma unroll
    for (int qq = 0; qq < 4; ++qq) {
      int g = tid + qq * 256;
      int row = g >> 4, grp = g & 15;
      const float* p = eps + row * BNP + grp * 9;
      float mn = p[0];
#pragma unroll
      for (int jj = 1; jj < 9; ++jj) mn = fminf(mn, p[jj]);
      local += mn;
    }
  }

#pragma unroll
  for (int off = 32; off > 0; off >>= 1) local += __shfl_down(local, off);
  __syncthreads();
  if (lane == 0) eps[wave] = local;
  __syncthreads();
  if (tid == 0) {
    float s = eps[0] + eps[1] + eps[2] + eps[3];
    // total group count = 8 * 2048 * 1152 / 9 = 2097152
    atomicAdd(out, s * (1.0f / 2097152.0f));
  }
}

extern "C" void kernel_launch(void* const* d_in, const int* in_sizes, int n_in,
                              void* d_out, int out_size, void* d_ws, size_t ws_size,
                              hipStream_t stream) {
  const float* x1 = (const float*)d_in[0];
  const float* x2 = (const float*)d_in[1];
  char* ws = (char*)d_ws;
  const size_t x1q_bytes = (size_t)NB * N1 * KD;  // 16777216
  const size_t x2q_bytes = (size_t)NB * N2 * KD;  // 9437184
  unsigned char* x1q = (unsigned char*)ws;
  unsigned char* x2q = (unsigned char*)(ws + x1q_bytes);
  float* sq1 = (float*)(ws + x1q_bytes + x2q_bytes);
  float* sq2 = (float*)(ws + x1q_bytes + x2q_bytes + (size_t)NB * N1 * 4);

  hipMemsetAsync(d_out, 0, sizeof(float), stream);
  convert_kernel<<<NB * (N1 + N2) / 4, 256, 0, stream>>>(x1, x2, x1q, x2q, sq1, sq2);
  dist_kernel<<<dim3(N1 / BM, N2 / BN, NB), 256, 0, stream>>>(x1q, x2q, sq1, sq2,
                                                              (float*)d_out);
}

// Round 5
// 160.142 us; speedup vs baseline: 2.1647x; 2.1647x over previous
//
#include <hip/hip_runtime.h>
#include <hip/hip_bf16.h>

#define NB 8
#define N1 2048
#define N2 1152
#define KD 1024
#define BM 256
#define BN 144
#define BNP 145  // padded epilogue stride

typedef __attribute__((ext_vector_type(4))) float f32x4;
typedef __attribute__((ext_vector_type(2))) long i64x2;

__device__ __forceinline__ unsigned pack4_fp8(float4 v) {
  int t = __builtin_amdgcn_cvt_pk_fp8_f32(v.x, v.y, 0, false);
  t = __builtin_amdgcn_cvt_pk_fp8_f32(v.z, v.w, t, true);
  return (unsigned)t;
}

// One WAVE per row. CONTIGUOUS float4 reads (k = 4*lane + 256*i); the k-block
// permutation is applied on the 4-byte fp8 write side (a wave's writes fully
// tile each contiguous 256 B region -> coalesced by the HW).
// Permuted layout per 64-value k-block: 16B group q holds k=[q*8..q*8+7] ++
// [32+q*8..32+q*8+7], so one b128 LDS read = both k-half MFMA fragments.
__global__ __launch_bounds__(256) void convert_kernel(
    const float* __restrict__ x1, const float* __restrict__ x2,
    unsigned char* __restrict__ x1q, unsigned char* __restrict__ x2q,
    float* __restrict__ sq1, float* __restrict__ sq2) {
  int wave = threadIdx.x >> 6, lane = threadIdx.x & 63;
  int row = blockIdx.x * 4 + wave;
  const float* src;
  unsigned char* dst;
  float* sqp;
  if (row < NB * N1) {
    src = x1 + (size_t)row * KD;
    dst = x1q + (size_t)row * KD;
    sqp = sq1 + row;
  } else {
    int r = row - NB * N1;
    src = x2 + (size_t)r * KD;
    dst = x2q + (size_t)r * KD;
    sqp = sq2 + r;
  }
  const float4* s4 = (const float4*)src;
  // lane covers k = i*256 + 4*lane .. +3  ->  within 64-block byte r=4*(lane&15),
  // permuted pos = q*16 + h*8 + (r&7), block base (lane>>4)*64.
  int r = 4 * (lane & 15);
  int q = (r & 31) >> 3;
  int h = r >> 5;
  int pos = (lane >> 4) * 64 + q * 16 + h * 8 + (r & 7);
  float s = 0.f;
#pragma unroll
  for (int i = 0; i < 4; ++i) {
    float4 v = s4[i * 64 + lane];
    *(unsigned*)(dst + i * 256 + pos) = pack4_fp8(v);
    s += v.x * v.x + v.y * v.y + v.z * v.z + v.w * v.w;
  }
#pragma unroll
  for (int off = 32; off > 0; off >>= 1) s += __shfl_down(s, off);
  if (lane == 0) *sqp = s;
}

__device__ __forceinline__ void async_copy16(const void* g, void* l) {
  __builtin_amdgcn_global_load_lds(
      (const __attribute__((address_space(1))) unsigned int*)g,
      (__attribute__((address_space(3))) unsigned int*)l, 16, 0, 0);
}

// Fused fp8 distance + group-min(9) + mean.
// Block tile 256(M) x 144(N), 4 waves; wave owns 64 M-rows = 4x9 acc tiles.
// CRITICAL: every loop touching acc[][] must be FULLY UNROLLED — any runtime
// index (R2..R4's `#pragma unroll 1` epilogue) defeats SROA and puts the
// whole accumulator array in scratch (1.2+ GB WRITE_SIZE, 3-10x slowdown).
// __launch_bounds__(256,2): 256-VGPR budget (acc 144 + frags + addr ~ 200).
// K-step 64 (fp8, 16 iters). LDS chunks 1 KB = 16 rows x 64 fp8, XOR swizzle
// (slot ^ (row>>1)&3) -> conflict-free b128 fragment reads (verified R2/R3).
__global__ __launch_bounds__(256, 2) void dist_kernel(
    const unsigned char* __restrict__ x1q, const unsigned char* __restrict__ x2q,
    const float* __restrict__ sq1, const float* __restrict__ sq2,
    float* __restrict__ out) {
  __shared__ __align__(16) char smem[64 * BNP * 4];  // 37120 B; staging uses 25600 B

  const int tid = threadIdx.x;
  const int wave = tid >> 6, lane = tid & 63;
  const int bm = blockIdx.x, bn = blockIdx.y, b = blockIdx.z;

  const unsigned char* Ag = x1q + ((size_t)b * N1 + bm * BM) * KD;
  const unsigned char* Bg = x2q + ((size_t)b * N2 + bn * BN) * KD;

  // staging: lane -> (row lr, 16B slot sl), fetch the swizzled global group
  const int lr = lane >> 2, sl = lane & 3;
  const int goff = (sl ^ ((lr >> 1) & 3)) * 16;

  // fragments: lane (fr, quad) reads swizzled slot -> global 16B group `quad`
  const int quad = lane >> 4, fr = lane & 15;
  const int fslot = (fr * 4 + (quad ^ ((fr >> 1) & 3))) * 16;

  f32x4 acc[4][9];
#pragma unroll
  for (int i = 0; i < 4; ++i)
#pragma unroll
    for (int j = 0; j < 9; ++j) {
      f32x4 z = {0.f, 0.f, 0.f, 0.f};
      acc[i][j] = z;
    }

  for (int k0 = 0; k0 < KD; k0 += 64) {
    // 25 chunks: 0..15 = A (256 rows), 16..24 = B (144 rows)
    for (int j = wave; j < 25; j += 4) {
      const unsigned char* g;
      if (j < 16)
        g = Ag + (size_t)(j * 16 + lr) * KD + k0 + goff;
      else
        g = Bg + (size_t)((j - 16) * 16 + lr) * KD + k0 + goff;
      async_copy16(g, smem + j * 1024 + lane * 16);
    }
    __syncthreads();

    i64x2 a[4];
#pragma unroll
    for (int tm = 0; tm < 4; ++tm)
      a[tm] = *(const i64x2*)(smem + (wave * 4 + tm) * 1024 + fslot);
#pragma unroll
    for (int tn = 0; tn < 9; ++tn) {
      i64x2 bf = *(const i64x2*)(smem + 16384 + tn * 1024 + fslot);
#pragma unroll
      for (int tm = 0; tm < 4; ++tm) {
        acc[tm][tn] = __builtin_amdgcn_mfma_f32_16x16x32_fp8_fp8(a[tm].x, bf.x, acc[tm][tn], 0, 0, 0);
        acc[tm][tn] = __builtin_amdgcn_mfma_f32_16x16x32_fp8_fp8(a[tm].y, bf.y, acc[tm][tn], 0, 0, 0);
      }
    }
    __syncthreads();
  }

  // ---- epilogue: d = sq1 + sq2 - 2*cross, min over 9-col groups, sum ----
  float s2[9];
#pragma unroll
  for (int tn = 0; tn < 9; ++tn)
    s2[tn] = sq2[(size_t)b * N2 + bn * BN + tn * 16 + fr];

  float s1v[4][4];
#pragma unroll
  for (int tm = 0; tm < 4; ++tm)
#pragma unroll
    for (int r = 0; r < 4; ++r)
      s1v[tm][r] = sq1[(size_t)b * N1 + bm * BM + wave * 64 + tm * 16 + quad * 4 + r];

  float* eps = (float*)smem;
  float local = 0.f;
#pragma unroll  // FULL unroll: acc indices must be compile-time (see header note)
  for (int tm = 0; tm < 4; ++tm) {
    __syncthreads();  // previous chunk / K-loop LDS fully consumed
    // D layout (16x16x32, dtype-independent): col = lane&15 (x2 row),
    // row = quad*4 + reg (x1 row). Chunk row = wave*16 + quad*4 + r.
#pragma unroll
    for (int tn = 0; tn < 9; ++tn)
#pragma unroll
      for (int r = 0; r < 4; ++r)
        eps[(wave * 16 + quad * 4 + r) * BNP + tn * 16 + fr] =
            s1v[tm][r] + s2[tn] - 2.0f * acc[tm][tn][r];
    __syncthreads();
    // 64 rows x 16 groups = 1024 groups, 4 per thread
#pragma unroll
    for (int qq = 0; qq < 4; ++qq) {
      int g = tid + qq * 256;
      int row = g >> 4, grp = g & 15;
      const float* p = eps + row * BNP + grp * 9;
      float mn = p[0];
#pragma unroll
      for (int jj = 1; jj < 9; ++jj) mn = fminf(mn, p[jj]);
      local += mn;
    }
  }

#pragma unroll
  for (int off = 32; off > 0; off >>= 1) local += __shfl_down(local, off);
  __syncthreads();
  if (lane == 0) eps[wave] = local;
  __syncthreads();
  if (tid == 0) {
    float s = eps[0] + eps[1] + eps[2] + eps[3];
    // total group count = 8 * 2048 * 1152 / 9 = 2097152
    atomicAdd(out, s * (1.0f / 2097152.0f));
  }
}

extern "C" void kernel_launch(void* const* d_in, const int* in_sizes, int n_in,
                              void* d_out, int out_size, void* d_ws, size_t ws_size,
                              hipStream_t stream) {
  const float* x1 = (const float*)d_in[0];
  const float* x2 = (const float*)d_in[1];
  char* ws = (char*)d_ws;
  const size_t x1q_bytes = (size_t)NB * N1 * KD;  // 16777216
  const size_t x2q_bytes = (size_t)NB * N2 * KD;  // 9437184
  unsigned char* x1q = (unsigned char*)ws;
  unsigned char* x2q = (unsigned char*)(ws + x1q_bytes);
  float* sq1 = (float*)(ws + x1q_bytes + x2q_bytes);
  float* sq2 = (float*)(ws + x1q_bytes + x2q_bytes + (size_t)NB * N1 * 4);

  hipMemsetAsync(d_out, 0, sizeof(float), stream);
  convert_kernel<<<NB * (N1 + N2) / 4, 256, 0, stream>>>(x1, x2, x1q, x2q, sq1, sq2);
  dist_kernel<<<dim3(N1 / BM, N2 / BN, NB), 256, 0, stream>>>(x1q, x2q, sq1, sq2,
                                                              (float*)d_out);
}